// Round 9
// baseline (764.975 us; speedup 1.0000x reference)
//
#include <hip/hip_runtime.h>

typedef unsigned short u16;
typedef short bf16x8 __attribute__((ext_vector_type(8)));
typedef float f32x4 __attribute__((ext_vector_type(4)));

#define EPSV 1e-3f

__device__ __forceinline__ float bf2f(u16 u) {
  union { unsigned int i; float f; } x; x.i = ((unsigned int)u) << 16; return x.f;
}
__device__ __forceinline__ u16 f2bf(float f) {
  union { float f; unsigned int i; } x; x.f = f;
  unsigned int r = x.i + 0x7fffu + ((x.i >> 16) & 1u);   // RNE
  return (u16)(r >> 16);
}

// wave-internal LDS handoff fence: drain DS pipe + stop compiler reordering
#define WAVE_FENCE() do { __builtin_amdgcn_s_waitcnt(0); __builtin_amdgcn_wave_barrier(); } while (0)

// ---------------------------------------------------------------------------
// Weight transform: fw (2,64,128,3,3) f32 ->
// fwT [set][qk][ky*3+kx][co][32ciq] bf16  (planar ci-quarters)
// ---------------------------------------------------------------------------
__global__ void twt_kernel(const float* __restrict__ fw, u16* __restrict__ fwT) {
  int i = blockIdx.x * blockDim.x + threadIdx.x;
  if (i >= 2 * 4 * 9 * 64 * 32) return;
  int ciq = i & 31;
  int r = i >> 5;
  int co = r & 63; r >>= 6;
  int tap = r % 9; r /= 9;
  int qk = r & 3;
  int set = r >> 2;
  int ci = qk * 32 + ciq;
  fwT[i] = f2bf(fw[(((set * 64 + co) * 128 + ci) * 9) + tap]);
}

// ---------------------------------------------------------------------------
// VFE via MFMA. One wave per voxel (4 waves/block, private LDS regions).
// (unchanged — verified correct, off the critical path)
// ---------------------------------------------------------------------------
__global__ __launch_bounds__(256, 2) void vfe_mfma_kernel(
    const float* __restrict__ vox, const int* __restrict__ npts,
    const float* __restrict__ w1, const float* __restrict__ g1, const float* __restrict__ b1,
    const float* __restrict__ rm1, const float* __restrict__ rv1,
    const float* __restrict__ w2, const float* __restrict__ g2, const float* __restrict__ b2,
    const float* __restrict__ rm2, const float* __restrict__ rv2,
    float* __restrict__ vf, int N)
{
  struct PerWave {
    u16 X[32 * 72];   // h1 bf16 [t][j], stride 72
    u16 F[32 * 40];   // feat bf16 [t][k], stride 40
    u16 G[64];        // gmax1 bf16
  };
  __shared__ __align__(16) union {
    struct { u16 W1T[64 * 40]; u16 W2T[64 * 136]; } w;
    PerWave r[4];
  } lds;

  const int tid = threadIdx.x;
  const int lane = tid & 63;
  const int wv = tid >> 6;
  const int m16 = lane & 15;
  const int q = lane >> 4;

  for (int i = tid; i < 64 * 40; i += 256) {
    int c = i / 40, k = i % 40;
    lds.w.W1T[i] = f2bf(k < 9 ? w1[k * 64 + c] : 0.f);
  }
  for (int i = tid; i < 64 * 136; i += 256) {
    int c = i / 136, j = i % 136;
    lds.w.W2T[i] = f2bf(j < 128 ? w2[j * 64 + c] : 0.f);
  }
  __syncthreads();

  bf16x8 bW1[4], bLo[4][2], bHi[4][2];
  float sc1[4], sh1[4], sc2[4], sh2[4];
#pragma unroll
  for (int nf = 0; nf < 4; ++nf) {
    int c = nf * 16 + m16;
    bW1[nf] = *(const bf16x8*)&lds.w.W1T[c * 40 + q * 8];
#pragma unroll
    for (int ks = 0; ks < 2; ++ks) {
      bLo[nf][ks] = *(const bf16x8*)&lds.w.W2T[c * 136 + ks * 32 + q * 8];
      bHi[nf][ks] = *(const bf16x8*)&lds.w.W2T[c * 136 + 64 + ks * 32 + q * 8];
    }
    float s1 = g1[c] * rsqrtf(rv1[c] + EPSV);
    sc1[nf] = s1; sh1[nf] = b1[c] - rm1[c] * s1;
    float s2 = g2[c] * rsqrtf(rv2[c] + EPSV);
    sc2[nf] = s2; sh2[nf] = b2[c] - rm2[c] * s2;
  }
  __syncthreads();

  u16* X = lds.r[wv].X;
  u16* F = lds.r[wv].F;
  u16* G = lds.r[wv].G;
  for (int i = lane; i < 640; i += 64) ((unsigned int*)F)[i] = 0u;

  const int wgid = blockIdx.x * 4 + wv;
  const int wstride = gridDim.x * 4;

  for (int v = wgid; v < N; v += wstride) {
    const int n = npts[v];
    float px = 0.f, py = 0.f, pz = 0.f, pw = 0.f;
    if (lane < 32) {
      float4 u = *(const float4*)(vox + ((size_t)v * 32 + lane) * 4);
      px = u.x; py = u.y; pz = u.z; pw = u.w;
    }
    float sx = px, sy = py, sz = pz;
#pragma unroll
    for (int off = 32; off >= 1; off >>= 1) {
      sx += __shfl_xor(sx, off);
      sy += __shfl_xor(sy, off);
      sz += __shfl_xor(sz, off);
    }
    float nf_ = (float)n;
    float mx = sx / nf_, my = sy / nf_, mz = sz / nf_;
    if (lane < 32) {
      float dx = px - mx, dy = py - my, dz = pz - mz;
      bf16x8 r0, r1;
      r0[0] = (short)f2bf(px); r0[1] = (short)f2bf(py);
      r0[2] = (short)f2bf(pz); r0[3] = (short)f2bf(pw);
      r0[4] = (short)f2bf(dx); r0[5] = (short)f2bf(dy);
      r0[6] = (short)f2bf(dz); r0[7] = (short)f2bf(dx);
      r1 = (bf16x8){0, 0, 0, 0, 0, 0, 0, 0};
      r1[0] = (short)f2bf(dy);
      *(bf16x8*)&F[lane * 40 + 0] = r0;
      *(bf16x8*)&F[lane * 40 + 8] = r1;
    }
    WAVE_FENCE();

    bf16x8 a1[2];
    a1[0] = *(const bf16x8*)&F[m16 * 40 + q * 8];
    a1[1] = *(const bf16x8*)&F[(16 + m16) * 40 + q * 8];
    f32x4 acc1[2][4];
#pragma unroll
    for (int mf = 0; mf < 2; ++mf)
#pragma unroll
      for (int nf = 0; nf < 4; ++nf) {
        acc1[mf][nf] = (f32x4){0.f, 0.f, 0.f, 0.f};
        acc1[mf][nf] = __builtin_amdgcn_mfma_f32_16x16x32_bf16(a1[mf], bW1[nf], acc1[mf][nf], 0, 0, 0);
      }

    float gmx[4] = {0.f, 0.f, 0.f, 0.f};
#pragma unroll
    for (int mf = 0; mf < 2; ++mf)
#pragma unroll
      for (int nf = 0; nf < 4; ++nf)
#pragma unroll
        for (int r = 0; r < 4; ++r) {
          float h = fmaxf(acc1[mf][nf][r] * sc1[nf] + sh1[nf], 0.f);
          gmx[nf] = fmaxf(gmx[nf], h);
          int t = mf * 16 + q * 4 + r;
          X[t * 72 + nf * 16 + m16] = f2bf(h);
        }
#pragma unroll
    for (int nf = 0; nf < 4; ++nf) {
      gmx[nf] = fmaxf(gmx[nf], __shfl_xor(gmx[nf], 16));
      gmx[nf] = fmaxf(gmx[nf], __shfl_xor(gmx[nf], 32));
    }
    if (q == 0) {
#pragma unroll
      for (int nf = 0; nf < 4; ++nf) G[nf * 16 + m16] = f2bf(gmx[nf]);
    }
    WAVE_FENCE();

    f32x4 ga[4];
#pragma unroll
    for (int nf = 0; nf < 4; ++nf) ga[nf] = (f32x4){0.f, 0.f, 0.f, 0.f};
#pragma unroll
    for (int ks = 0; ks < 2; ++ks) {
      bf16x8 ag = (bf16x8){0, 0, 0, 0, 0, 0, 0, 0};
      if (m16 == 0) ag = *(const bf16x8*)&G[ks * 32 + q * 8];
#pragma unroll
      for (int nf = 0; nf < 4; ++nf)
        ga[nf] = __builtin_amdgcn_mfma_f32_16x16x32_bf16(ag, bHi[nf][ks], ga[nf], 0, 0, 0);
    }
    float gt[4];
#pragma unroll
    for (int nf = 0; nf < 4; ++nf) {
      float s = ga[nf][0] + ga[nf][1] + ga[nf][2] + ga[nf][3];
      s += __shfl_xor(s, 16);
      s += __shfl_xor(s, 32);
      gt[nf] = s;
    }

    f32x4 acc2[2][4];
#pragma unroll
    for (int mf = 0; mf < 2; ++mf)
#pragma unroll
      for (int nf = 0; nf < 4; ++nf)
        acc2[mf][nf] = (f32x4){gt[nf], gt[nf], gt[nf], gt[nf]};
#pragma unroll
    for (int ks = 0; ks < 2; ++ks) {
      bf16x8 a2[2];
      a2[0] = *(const bf16x8*)&X[m16 * 72 + ks * 32 + q * 8];
      a2[1] = *(const bf16x8*)&X[(16 + m16) * 72 + ks * 32 + q * 8];
#pragma unroll
      for (int mf = 0; mf < 2; ++mf)
#pragma unroll
        for (int nf = 0; nf < 4; ++nf)
          acc2[mf][nf] = __builtin_amdgcn_mfma_f32_16x16x32_bf16(a2[mf], bLo[nf][ks], acc2[mf][nf], 0, 0, 0);
    }

    float vm[4] = {0.f, 0.f, 0.f, 0.f};
#pragma unroll
    for (int mf = 0; mf < 2; ++mf)
#pragma unroll
      for (int nf = 0; nf < 4; ++nf)
#pragma unroll
        for (int r = 0; r < 4; ++r) {
          int t = mf * 16 + q * 4 + r;
          float h2 = fmaxf(acc2[mf][nf][r] * sc2[nf] + sh2[nf], 0.f);
          if (t < n) vm[nf] = fmaxf(vm[nf], h2);
        }
#pragma unroll
    for (int nf = 0; nf < 4; ++nf) {
      vm[nf] = fmaxf(vm[nf], __shfl_xor(vm[nf], 16));
      vm[nf] = fmaxf(vm[nf], __shfl_xor(vm[nf], 32));
    }
    float outv = (q == 0) ? vm[0] : (q == 1) ? vm[1] : (q == 2) ? vm[2] : vm[3];
    vf[(size_t)v * 64 + q * 16 + m16] = outv;
    __builtin_amdgcn_wave_barrier();
  }
}

// ---------------------------------------------------------------------------
// Scatter pass 1: last-write-wins == max voxel index per cell
// ---------------------------------------------------------------------------
__global__ void winner_kernel(const int* __restrict__ coords, int* __restrict__ win,
                              int N, int H, int W) {
  int v = blockIdx.x * blockDim.x + threadIdx.x;
  if (v >= N) return;
  int b = coords[v * 4 + 0];
  int y = min(max(coords[v * 4 + 2], 0), H - 1);
  int x = min(max(coords[v * 4 + 3], 0), W - 1);
  atomicMax(&win[(b * H + y) * W + x], v);
}

// ---------------------------------------------------------------------------
// Scatter pass 2 + zero-fill, vectorized: thread = 8 channels (16B store).
// planar!=0: dst is 4 planes of [cell][32ci]; planar==0: dense 64-ch NHWC.
// ---------------------------------------------------------------------------
__global__ void fill_kernel(const int* __restrict__ win, const float* __restrict__ vf,
                            u16* __restrict__ dst, int cells, size_t ps, int planar) {
  int i = blockIdx.x * blockDim.x + threadIdx.x;
  if (i >= cells * 8) return;
  int cell = i >> 3, c8 = (i & 7) * 8;
  int wv = win[cell];
  bf16x8 o = (bf16x8){0, 0, 0, 0, 0, 0, 0, 0};
  if (wv >= 0) {
    const float* p = vf + (size_t)wv * 64 + c8;
    float4 v0 = *(const float4*)p;
    float4 v1 = *(const float4*)(p + 4);
    o[0] = (short)f2bf(v0.x); o[1] = (short)f2bf(v0.y);
    o[2] = (short)f2bf(v0.z); o[3] = (short)f2bf(v0.w);
    o[4] = (short)f2bf(v1.x); o[5] = (short)f2bf(v1.y);
    o[6] = (short)f2bf(v1.z); o[7] = (short)f2bf(v1.w);
  }
  u16* d = planar ? (dst + (size_t)(c8 >> 5) * ps + (size_t)cell * 32 + (c8 & 31))
                  : (dst + (size_t)cell * 64 + c8);
  *(bf16x8*)d = o;
}

// ---------------------------------------------------------------------------
// Bilinear 2x upsample: src dense 64-ch NHWC; dst planar quarters 2,3
// (ch 64..127) of a 4-plane [cell][32ci] buffer with plane stride ps (u16).
// ---------------------------------------------------------------------------
__global__ void upsample_kernel(const u16* __restrict__ src, u16* __restrict__ dst,
                                int Hc, int Wc, size_t ps, int total8) {
  int i = blockIdx.x * blockDim.x + threadIdx.x;
  if (i >= total8) return;
  int c8 = (i & 7) * 8;
  int px = i >> 3;
  int W2 = Wc * 2, H2 = Hc * 2;
  int x = px % W2; int t = px / W2; int y = t % H2; int n = t / H2;
  int ky = y >> 1, kx = x >> 1;
  int ya, yb, xa, xb; float wya, wxa;
  if ((y & 1) == 0) { ya = ky > 0 ? ky - 1 : 0; yb = ky; wya = 0.25f; }
  else              { ya = ky; yb = (ky + 1 < Hc) ? ky + 1 : Hc - 1; wya = 0.75f; }
  if ((x & 1) == 0) { xa = kx > 0 ? kx - 1 : 0; xb = kx; wxa = 0.25f; }
  else              { xa = kx; xb = (kx + 1 < Wc) ? kx + 1 : Wc - 1; wxa = 0.75f; }
  float wyb = 1.f - wya, wxb = 1.f - wxa;
  const u16* sp = src + c8;
  bf16x8 vaa = *(const bf16x8*)&sp[((size_t)(n * Hc + ya) * Wc + xa) * 64];
  bf16x8 vab = *(const bf16x8*)&sp[((size_t)(n * Hc + ya) * Wc + xb) * 64];
  bf16x8 vba = *(const bf16x8*)&sp[((size_t)(n * Hc + yb) * Wc + xa) * 64];
  bf16x8 vbb = *(const bf16x8*)&sp[((size_t)(n * Hc + yb) * Wc + xb) * 64];
  bf16x8 o;
#pragma unroll
  for (int j = 0; j < 8; ++j) {
    float v = wya * (wxa * bf2f((u16)vaa[j]) + wxb * bf2f((u16)vab[j])) +
              wyb * (wxa * bf2f((u16)vba[j]) + wxb * bf2f((u16)vbb[j]));
    o[j] = (short)f2bf(v);
  }
  *(bf16x8*)&dst[(size_t)(2 + (c8 >> 5)) * ps + (size_t)px * 32 + (c8 & 31)] = o;
}

// ---------------------------------------------------------------------------
// Conv3x3 + BN + ReLU, implicit GEMM with bf16 MFMA 16x16x32.
//
// Round-9 = round-8 resubmit (container infra failure, no kernel verdict).
// OCCUPANCY unlock: reported VGPR_Count is ARCH regs only — unified = arch +
// AGPR(acc). r5: 112+64=176, r7: 128+128=256 -> both register-locked to
// 2 waves/SIMD; every pipe <=25% busy => latency-bound. Fix: round-5 wave
// shape (M=64, acc=64 AGPR, 8 reads:16 MFMA) on the PLANAR ci-quarter
// layout (r7-proven, FETCH clean):
//  - LDS: A halo 340px x 64B pair-packed (21,760) + B per-tap dbuf 2x4,096
//    = 29,952 B -> 3 blocks/CU easily.
//  - Quartered staging needs fewer arch regs (1 B-chunk/thread, no hf state)
//    -> target ~100-106 arch; 64 acc -> unified <=170 = 3 waves/SIMD.
//  - __launch_bounds__(256,3): watch WRITE_SIZE for spill.
// Per quarter: {stage A + B[0]; barrier; 9 taps: T14 B-prefetch -> reg,
// 8 ds_read + 16 MFMA, ds_write B[next], barrier} — r5 cadence (1.78M confl).
// ---------------------------------------------------------------------------
template<int H, int W, bool NCHW_OUT>
__global__ __launch_bounds__(256, 3) void conv_kernel(
    const u16* __restrict__ in, const u16* __restrict__ wT,
    const float* __restrict__ fg, const float* __restrict__ fb,
    const float* __restrict__ fm, const float* __restrict__ fv,
    void* __restrict__ outv)
{
  constexpr int XT = 32, YT = 8;
  constexpr int XTILES = (W + XT - 1) / XT;
  constexpr int YTILES = H / YT;
  constexpr int HC = XT + 2;                   // 34 halo cols
  constexpr int NPX = (YT + 2) * HC;           // 340 halo positions
  const size_t PS = (size_t)4 * H * W * 32;    // plane stride (u16), batch=4
  __shared__ __align__(16) union {
    struct { char A[(NPX / 2) * 128]; char B[2][4096]; } s;  // 21,760 + 8,192 = 29,952
    float T[4 * 32 * 33];                      // 16,896 (NCHW epilogue, half-co)
  } lds;

  const int tid = threadIdx.x;
  const int lane = tid & 63;
  const int wv = tid >> 6;                     // wave -> rows [2wv, 2wv+1]
  const int m16 = lane & 15;
  const int q = lane >> 4;

  int bid = blockIdx.x;
  const int xt = bid % XTILES; bid /= XTILES;
  const int yt = bid % YTILES;
  const int n = bid / YTILES;
  const int x0 = xt * XT, y0 = yt * YT;

  // per-lane A-frag halo position (M-pos = mf*16+m16 -> row = mf>>1, px)
  int lin[4];
#pragma unroll
  for (int mf = 0; mf < 4; ++mf)
    lin[mf] = (2 * wv + (mf >> 1)) * HC + ((mf & 1) << 4) + m16;

  // per-lane B-frag byte base within a tap plane (co = nf*16+m16, k-slice q)
  const int bbase = ((m16 >> 1) << 7) + (((((m16 & 1) << 2) + q) ^ ((m16 >> 1) & 7)) << 4);

  f32x4 acc[4][4];
#pragma unroll
  for (int mf = 0; mf < 4; ++mf)
#pragma unroll
    for (int nf = 0; nf < 4; ++nf)
      acc[mf][nf] = (f32x4){0.f, 0.f, 0.f, 0.f};

  const int bco = tid >> 2, bs = tid & 3;      // B staging chunk coords
  const int bslot = ((((bco & 1) << 2) + bs) ^ ((bco >> 1) & 7));
  const int bldst = ((bco >> 1) << 7) + (bslot << 4);
  const int bgsrc = bco * 32 + bs * 8;         // u16 offset within tap plane

  for (int qk = 0; qk < 4; ++qk) {
    // protected by previous quarter's tap-8 barrier (or kernel entry)
    const u16* inq = in + (size_t)qk * PS;
    const u16* wq = wT + qk * (9 * 64 * 32);
    {
      // stage A: 340 px x 32 ci (64B/px), pair-packed swizzled 128B rows
#pragma unroll
      for (int it = 0; it < 6; ++it) {
        int c = tid + it * 256;
        if (c < NPX * 4) {
          int p = c >> 2, s = c & 3;
          int r = p / HC, xx = p - r * HC;
          int gy = y0 - 1 + r, gx = x0 - 1 + xx;
          uint4 v = make_uint4(0, 0, 0, 0);
          if (gy >= 0 && gy < H && gx >= 0 && gx < W)
            v = *(const uint4*)(inq + ((size_t)((n * H + gy) * W + gx)) * 32 + s * 8);
          int slot = (((p & 1) << 2) + s) ^ ((p >> 1) & 7);
          *(uint4*)(lds.s.A + ((p >> 1) << 7) + (slot << 4)) = v;
        }
      }
      // stage B tap 0 -> buffer 0 (one 16B chunk per thread)
      uint4 v = *(const uint4*)(wq + bgsrc);
      *(uint4*)(lds.s.B[0] + bldst) = v;
    }
    __syncthreads();                           // A + B[0] visible

#pragma unroll
    for (int tap = 0; tap < 9; ++tap) {
      // T14 issue-early: next tap's B -> reg before the MFMA cluster
      uint4 bv;
      if (tap < 8) bv = *(const uint4*)(wq + (tap + 1) * 2048 + bgsrc);
      const int tapofs = (tap / 3) * HC + (tap % 3);
      const char* Bb = lds.s.B[tap & 1];
      bf16x8 b[4], a[4];
#pragma unroll
      for (int nf = 0; nf < 4; ++nf)
        b[nf] = *(const bf16x8*)(Bb + (nf << 10) + bbase);
#pragma unroll
      for (int mf = 0; mf < 4; ++mf) {
        int hp = lin[mf] + tapofs;
        int slot = (((hp & 1) << 2) + q) ^ ((hp >> 1) & 7);
        a[mf] = *(const bf16x8*)(lds.s.A + ((hp >> 1) << 7) + (slot << 4));
      }
#pragma unroll
      for (int mf = 0; mf < 4; ++mf)
#pragma unroll
        for (int nf = 0; nf < 4; ++nf)
          acc[mf][nf] = __builtin_amdgcn_mfma_f32_16x16x32_bf16(a[mf], b[nf], acc[mf][nf], 0, 0, 0);
      // write-late: prefetched B into the other buffer (its readers ran in
      // tap-1, protected by tap-1's barrier)
      if (tap < 8) *(uint4*)(lds.s.B[(tap + 1) & 1] + bldst) = bv;
      __syncthreads();                         // B[next] visible; tap reads done
    }
  }

  // BN scale/shift in epilogue (keeps main-loop VGPR pressure down)
  float sc[4], sh[4];
#pragma unroll
  for (int nf = 0; nf < 4; ++nf) {
    int co = nf * 16 + m16;
    float s = fg[co] * rsqrtf(fv[co] + EPSV);
    sc[nf] = s;
    sh[nf] = fb[co] - fm[co] * s;
  }

  if (!NCHW_OUT) {
    // NHWC(64) bf16 direct store (internal fused1 buffer)
    u16* out = (u16*)outv;
#pragma unroll
    for (int mf = 0; mf < 4; ++mf) {
      int y = y0 + wv * 2 + (mf >> 1);
#pragma unroll
      for (int nf = 0; nf < 4; ++nf)
#pragma unroll
        for (int r = 0; r < 4; ++r) {
          int px = ((mf & 1) << 4) + q * 4 + r;
          int x = x0 + px;
          if (x < W) {
            int co = nf * 16 + m16;
            float v = fmaxf(acc[mf][nf][r] * sc[nf] + sh[nf], 0.f);
            out[((size_t)(n * H + y) * W + x) * 64 + co] = f2bf(v);
          }
        }
    }
  } else {
    // NCHW f32 d_out: per-row, per-co-half transpose via wave-private LDS
    // (32x33 floats per wave = 16,896 total, fits under the A+B union)
    __syncthreads();                           // all tap reads done; union reuse safe
    float* out = (float*)outv;
    float* T = &lds.T[wv * 32 * 33];
#pragma unroll
    for (int rr = 0; rr < 2; ++rr) {
      int y = y0 + wv * 2 + rr;
#pragma unroll
      for (int half = 0; half < 2; ++half) {
#pragma unroll
        for (int nfh = 0; nfh < 2; ++nfh) {
          int nf = half * 2 + nfh;
#pragma unroll
          for (int xc = 0; xc < 2; ++xc) {
            int mf = rr * 2 + xc;
#pragma unroll
            for (int r = 0; r < 4; ++r) {
              int px = (xc << 4) + q * 4 + r;
              int col = nfh * 16 + m16;
              T[col * 33 + px] = fmaxf(acc[mf][nf][r] * sc[nf] + sh[nf], 0.f);
            }
          }
        }
        WAVE_FENCE();
        const int px = lane & 31, co2 = lane >> 5;
        int x = x0 + px;
#pragma unroll 4
        for (int it = 0; it < 16; ++it) {
          int col = it * 2 + co2;
          int co = half * 32 + col;
          float v = T[col * 33 + px];
          if (x < W) out[((size_t)(n * 64 + co) * H + y) * W + x] = v;
        }
        WAVE_FENCE();
      }
    }
  }
}

// ---------------------------------------------------------------------------
extern "C" void kernel_launch(void* const* d_in, const int* in_sizes, int n_in,
                              void* d_out, int out_size, void* d_ws, size_t ws_size,
                              hipStream_t stream) {
  int I_vox[3], I_np[3], I_co[3];
  int I_w1, I_g1, I_b1, I_rm1, I_rv1, I_w2, I_g2, I_b2, I_rm2, I_rv2;
  int I_fw, I_fg, I_fb, I_fm, I_fv;
  if (in_sizes[1] == 40000) {
    I_vox[0] = 0; I_np[0] = 1; I_co[0] = 2;
    I_vox[1] = 3; I_np[1] = 4; I_co[1] = 5;
    I_vox[2] = 6; I_np[2] = 7; I_co[2] = 8;
    I_w1 = 9; I_g1 = 10; I_b1 = 11; I_rm1 = 12; I_rv1 = 13;
    I_w2 = 14; I_g2 = 15; I_b2 = 16; I_rm2 = 17; I_rv2 = 18;
    I_fw = 19; I_fg = 20; I_fb = 21; I_fm = 22; I_fv = 23;
  } else {
    I_vox[0] = 0; I_vox[1] = 1; I_vox[2] = 2;
    I_w1 = 3; I_g1 = 4; I_b1 = 5; I_rm1 = 6; I_rv1 = 7;
    I_w2 = 8; I_g2 = 9; I_b2 = 10; I_rm2 = 11; I_rv2 = 12;
    I_fw = 13; I_fg = 14; I_fb = 15; I_fm = 16; I_fv = 17;
    I_np[0] = 18; I_np[1] = 19; I_np[2] = 20;
    I_co[0] = 21; I_co[1] = 22; I_co[2] = 23;
  }

  const int HS[3] = {496, 248, 124};
  const int WS[3] = {432, 216, 108};
  int Nv[3];
  for (int s = 0; s < 3; ++s) Nv[s] = in_sizes[I_np[s]];

  char* wsp = (char*)d_ws;
  size_t off = 0;
  auto take = [&](size_t bytes) -> void* {
    void* p = wsp + off;
    off = (off + bytes + 255) & ~(size_t)255;
    return p;
  };
  float* vf[3]; int* win[3];
  for (int s = 0; s < 3; ++s) vf[s] = (float*)take((size_t)Nv[s] * 64 * 4);
  int cells[3];
  for (int s = 0; s < 3; ++s) {
    cells[s] = 4 * HS[s] * WS[s];
    win[s] = (int*)take((size_t)cells[s] * 4);
  }
  u16* buf0 = (u16*)take((size_t)cells[0] * 128 * 2);   // 4 planes x (cells0 x 32ci) bf16
  u16* buf1 = (u16*)take((size_t)cells[1] * 128 * 2);   // 4 planes x (cells1 x 32ci)
  u16* g2b  = (u16*)take((size_t)cells[2] * 64 * 2);    // dense (4,124,108,64)
  u16* fus1 = (u16*)take((size_t)cells[1] * 64 * 2);    // dense (4,248,216,64)
  u16* fwT  = (u16*)take((size_t)2 * 4 * 9 * 64 * 32 * 2);

  const float* W1 = (const float*)d_in[I_w1];
  const float* G1 = (const float*)d_in[I_g1];
  const float* B1 = (const float*)d_in[I_b1];
  const float* RM1 = (const float*)d_in[I_rm1];
  const float* RV1 = (const float*)d_in[I_rv1];
  const float* W2 = (const float*)d_in[I_w2];
  const float* G2 = (const float*)d_in[I_g2];
  const float* B2 = (const float*)d_in[I_b2];
  const float* RM2 = (const float*)d_in[I_rm2];
  const float* RV2 = (const float*)d_in[I_rv2];
  const float* FW = (const float*)d_in[I_fw];
  const float* FG = (const float*)d_in[I_fg];
  const float* FB = (const float*)d_in[I_fb];
  const float* FM = (const float*)d_in[I_fm];
  const float* FV = (const float*)d_in[I_fv];

  for (int s = 0; s < 3; ++s)
    hipMemsetAsync(win[s], 0xFF, (size_t)cells[s] * 4, stream);

  twt_kernel<<<(2 * 4 * 9 * 64 * 32 + 255) / 256, 256, 0, stream>>>(FW, fwT);

  for (int s = 0; s < 3; ++s) {
    int blocks = (Nv[s] + 3) / 4;
    if (blocks > 1024) blocks = 1024;
    vfe_mfma_kernel<<<blocks, 256, 0, stream>>>(
        (const float*)d_in[I_vox[s]], (const int*)d_in[I_np[s]],
        W1 + s * 9 * 64, G1 + s * 64, B1 + s * 64, RM1 + s * 64, RV1 + s * 64,
        W2 + s * 128 * 64, G2 + s * 64, B2 + s * 64, RM2 + s * 64, RV2 + s * 64,
        vf[s], Nv[s]);
  }
  for (int s = 0; s < 3; ++s) {
    winner_kernel<<<(Nv[s] + 255) / 256, 256, 0, stream>>>(
        (const int*)d_in[I_co[s]], win[s], Nv[s], HS[s], WS[s]);
  }
  const size_t ps0 = (size_t)cells[0] * 32;
  const size_t ps1 = (size_t)cells[1] * 32;
  fill_kernel<<<(cells[0] * 8 + 255) / 256, 256, 0, stream>>>(win[0], vf[0], buf0, cells[0], ps0, 1);
  fill_kernel<<<(cells[1] * 8 + 255) / 256, 256, 0, stream>>>(win[1], vf[1], buf1, cells[1], ps1, 1);
  fill_kernel<<<(cells[2] * 8 + 255) / 256, 256, 0, stream>>>(win[2], vf[2], g2b, cells[2], 0, 0);

  {   // upsample g2 (124,108) -> buf1 planes 2,3 (248,216)
    int total8 = cells[1] * 8;
    upsample_kernel<<<(total8 + 255) / 256, 256, 0, stream>>>(g2b, buf1, 124, 108, ps1, total8);
  }
  conv_kernel<248, 216, false><<<4 * (248 / 8) * 7, 256, 0, stream>>>(
      buf1, fwT + 4 * 9 * 64 * 32, FG + 64, FB + 64, FM + 64, FV + 64, fus1);
  {   // upsample fused1 (248,216) -> buf0 planes 2,3 (496,432)
    int total8 = cells[0] * 8;
    upsample_kernel<<<(total8 + 255) / 256, 256, 0, stream>>>(fus1, buf0, 248, 216, ps0, total8);
  }
  conv_kernel<496, 432, true><<<4 * (496 / 8) * 14, 256, 0, stream>>>(
      buf0, fwT, FG, FB, FM, FV, (float*)d_out);
}

// Round 10
// 711.176 us; speedup vs baseline: 1.0756x; 1.0756x over previous
//
#include <hip/hip_runtime.h>

typedef unsigned short u16;
typedef short bf16x8 __attribute__((ext_vector_type(8)));
typedef float f32x4 __attribute__((ext_vector_type(4)));

#define EPSV 1e-3f

__device__ __forceinline__ float bf2f(u16 u) {
  union { unsigned int i; float f; } x; x.i = ((unsigned int)u) << 16; return x.f;
}
__device__ __forceinline__ u16 f2bf(float f) {
  union { float f; unsigned int i; } x; x.f = f;
  unsigned int r = x.i + 0x7fffu + ((x.i >> 16) & 1u);   // RNE
  return (u16)(r >> 16);
}

// wave-internal LDS handoff fence: drain DS pipe + stop compiler reordering
#define WAVE_FENCE() do { __builtin_amdgcn_s_waitcnt(0); __builtin_amdgcn_wave_barrier(); } while (0)

// ---------------------------------------------------------------------------
// VFE LDS layout (identical to the verified standalone kernel)
// ---------------------------------------------------------------------------
struct VfePerWave {
  u16 X[32 * 72];   // h1 bf16 [t][j], stride 72
  u16 F[32 * 40];   // feat bf16 [t][k], stride 40
  u16 G[64];        // gmax1 bf16
};
union VfeLds {
  struct { u16 W1T[64 * 40]; u16 W2T[64 * 136]; } w;
  VfePerWave r[4];
};

// ---------------------------------------------------------------------------
// VFE body (identical logic to the verified r9 kernel; lb = local block id,
// fixed 1024 blocks per scale -> wstride 4096)
// ---------------------------------------------------------------------------
__device__ void vfe_body(VfeLds& lds, int lb,
    const float* __restrict__ vox, const int* __restrict__ npts,
    const float* __restrict__ w1, const float* __restrict__ g1, const float* __restrict__ b1,
    const float* __restrict__ rm1, const float* __restrict__ rv1,
    const float* __restrict__ w2, const float* __restrict__ g2, const float* __restrict__ b2,
    const float* __restrict__ rm2, const float* __restrict__ rv2,
    float* __restrict__ vf, int N)
{
  const int tid = threadIdx.x;
  const int lane = tid & 63;
  const int wv = tid >> 6;
  const int m16 = lane & 15;
  const int q = lane >> 4;

  for (int i = tid; i < 64 * 40; i += 256) {
    int c = i / 40, k = i % 40;
    lds.w.W1T[i] = f2bf(k < 9 ? w1[k * 64 + c] : 0.f);
  }
  for (int i = tid; i < 64 * 136; i += 256) {
    int c = i / 136, j = i % 136;
    lds.w.W2T[i] = f2bf(j < 128 ? w2[j * 64 + c] : 0.f);
  }
  __syncthreads();

  bf16x8 bW1[4], bLo[4][2], bHi[4][2];
  float sc1[4], sh1[4], sc2[4], sh2[4];
#pragma unroll
  for (int nf = 0; nf < 4; ++nf) {
    int c = nf * 16 + m16;
    bW1[nf] = *(const bf16x8*)&lds.w.W1T[c * 40 + q * 8];
#pragma unroll
    for (int ks = 0; ks < 2; ++ks) {
      bLo[nf][ks] = *(const bf16x8*)&lds.w.W2T[c * 136 + ks * 32 + q * 8];
      bHi[nf][ks] = *(const bf16x8*)&lds.w.W2T[c * 136 + 64 + ks * 32 + q * 8];
    }
    float s1 = g1[c] * rsqrtf(rv1[c] + EPSV);
    sc1[nf] = s1; sh1[nf] = b1[c] - rm1[c] * s1;
    float s2 = g2[c] * rsqrtf(rv2[c] + EPSV);
    sc2[nf] = s2; sh2[nf] = b2[c] - rm2[c] * s2;
  }
  __syncthreads();

  u16* X = lds.r[wv].X;
  u16* F = lds.r[wv].F;
  u16* G = lds.r[wv].G;
  for (int i = lane; i < 640; i += 64) ((unsigned int*)F)[i] = 0u;

  const int wgid = lb * 4 + wv;
  const int wstride = 4096;

  for (int v = wgid; v < N; v += wstride) {
    const int n = npts[v];
    float px = 0.f, py = 0.f, pz = 0.f, pw = 0.f;
    if (lane < 32) {
      float4 u = *(const float4*)(vox + ((size_t)v * 32 + lane) * 4);
      px = u.x; py = u.y; pz = u.z; pw = u.w;
    }
    float sx = px, sy = py, sz = pz;
#pragma unroll
    for (int off = 32; off >= 1; off >>= 1) {
      sx += __shfl_xor(sx, off);
      sy += __shfl_xor(sy, off);
      sz += __shfl_xor(sz, off);
    }
    float nf_ = (float)n;
    float mx = sx / nf_, my = sy / nf_, mz = sz / nf_;
    if (lane < 32) {
      float dx = px - mx, dy = py - my, dz = pz - mz;
      bf16x8 r0, r1;
      r0[0] = (short)f2bf(px); r0[1] = (short)f2bf(py);
      r0[2] = (short)f2bf(pz); r0[3] = (short)f2bf(pw);
      r0[4] = (short)f2bf(dx); r0[5] = (short)f2bf(dy);
      r0[6] = (short)f2bf(dz); r0[7] = (short)f2bf(dx);
      r1 = (bf16x8){0, 0, 0, 0, 0, 0, 0, 0};
      r1[0] = (short)f2bf(dy);
      *(bf16x8*)&F[lane * 40 + 0] = r0;
      *(bf16x8*)&F[lane * 40 + 8] = r1;
    }
    WAVE_FENCE();

    bf16x8 a1[2];
    a1[0] = *(const bf16x8*)&F[m16 * 40 + q * 8];
    a1[1] = *(const bf16x8*)&F[(16 + m16) * 40 + q * 8];
    f32x4 acc1[2][4];
#pragma unroll
    for (int mf = 0; mf < 2; ++mf)
#pragma unroll
      for (int nf = 0; nf < 4; ++nf) {
        acc1[mf][nf] = (f32x4){0.f, 0.f, 0.f, 0.f};
        acc1[mf][nf] = __builtin_amdgcn_mfma_f32_16x16x32_bf16(a1[mf], bW1[nf], acc1[mf][nf], 0, 0, 0);
      }

    float gmx[4] = {0.f, 0.f, 0.f, 0.f};
#pragma unroll
    for (int mf = 0; mf < 2; ++mf)
#pragma unroll
      for (int nf = 0; nf < 4; ++nf)
#pragma unroll
        for (int r = 0; r < 4; ++r) {
          float h = fmaxf(acc1[mf][nf][r] * sc1[nf] + sh1[nf], 0.f);
          gmx[nf] = fmaxf(gmx[nf], h);
          int t = mf * 16 + q * 4 + r;
          X[t * 72 + nf * 16 + m16] = f2bf(h);
        }
#pragma unroll
    for (int nf = 0; nf < 4; ++nf) {
      gmx[nf] = fmaxf(gmx[nf], __shfl_xor(gmx[nf], 16));
      gmx[nf] = fmaxf(gmx[nf], __shfl_xor(gmx[nf], 32));
    }
    if (q == 0) {
#pragma unroll
      for (int nf = 0; nf < 4; ++nf) G[nf * 16 + m16] = f2bf(gmx[nf]);
    }
    WAVE_FENCE();

    f32x4 ga[4];
#pragma unroll
    for (int nf = 0; nf < 4; ++nf) ga[nf] = (f32x4){0.f, 0.f, 0.f, 0.f};
#pragma unroll
    for (int ks = 0; ks < 2; ++ks) {
      bf16x8 ag = (bf16x8){0, 0, 0, 0, 0, 0, 0, 0};
      if (m16 == 0) ag = *(const bf16x8*)&G[ks * 32 + q * 8];
#pragma unroll
      for (int nf = 0; nf < 4; ++nf)
        ga[nf] = __builtin_amdgcn_mfma_f32_16x16x32_bf16(ag, bHi[nf][ks], ga[nf], 0, 0, 0);
    }
    float gt[4];
#pragma unroll
    for (int nf = 0; nf < 4; ++nf) {
      float s = ga[nf][0] + ga[nf][1] + ga[nf][2] + ga[nf][3];
      s += __shfl_xor(s, 16);
      s += __shfl_xor(s, 32);
      gt[nf] = s;
    }

    f32x4 acc2[2][4];
#pragma unroll
    for (int mf = 0; mf < 2; ++mf)
#pragma unroll
      for (int nf = 0; nf < 4; ++nf)
        acc2[mf][nf] = (f32x4){gt[nf], gt[nf], gt[nf], gt[nf]};
#pragma unroll
    for (int ks = 0; ks < 2; ++ks) {
      bf16x8 a2[2];
      a2[0] = *(const bf16x8*)&X[m16 * 72 + ks * 32 + q * 8];
      a2[1] = *(const bf16x8*)&X[(16 + m16) * 72 + ks * 32 + q * 8];
#pragma unroll
      for (int mf = 0; mf < 2; ++mf)
#pragma unroll
        for (int nf = 0; nf < 4; ++nf)
          acc2[mf][nf] = __builtin_amdgcn_mfma_f32_16x16x32_bf16(a2[mf], bLo[nf][ks], acc2[mf][nf], 0, 0, 0);
    }

    float vm[4] = {0.f, 0.f, 0.f, 0.f};
#pragma unroll
    for (int mf = 0; mf < 2; ++mf)
#pragma unroll
      for (int nf = 0; nf < 4; ++nf)
#pragma unroll
        for (int r = 0; r < 4; ++r) {
          int t = mf * 16 + q * 4 + r;
          float h2 = fmaxf(acc2[mf][nf][r] * sc2[nf] + sh2[nf], 0.f);
          if (t < n) vm[nf] = fmaxf(vm[nf], h2);
        }
#pragma unroll
    for (int nf = 0; nf < 4; ++nf) {
      vm[nf] = fmaxf(vm[nf], __shfl_xor(vm[nf], 16));
      vm[nf] = fmaxf(vm[nf], __shfl_xor(vm[nf], 32));
    }
    float outv = (q == 0) ? vm[0] : (q == 1) ? vm[1] : (q == 2) ? vm[2] : vm[3];
    vf[(size_t)v * 64 + q * 16 + m16] = outv;
    __builtin_amdgcn_wave_barrier();
  }
}

// ---------------------------------------------------------------------------
// Mega-kernel 1: twt (576 blocks) + VFE all 3 scales (3x1024 blocks, running
// CONCURRENTLY) + winner all 3 scales. Replaces 7 dispatches with 1.
// Role is uniform per block -> no divergence; bodies identical to verified
// standalone kernels.
// ---------------------------------------------------------------------------
__global__ __launch_bounds__(256, 2) void fused1_kernel(
    const float* __restrict__ fw, u16* __restrict__ fwT,
    const float* __restrict__ vox0, const float* __restrict__ vox1, const float* __restrict__ vox2,
    const int* __restrict__ np0, const int* __restrict__ np1, const int* __restrict__ np2,
    const float* __restrict__ W1, const float* __restrict__ G1, const float* __restrict__ B1,
    const float* __restrict__ RM1, const float* __restrict__ RV1,
    const float* __restrict__ W2, const float* __restrict__ G2, const float* __restrict__ B2,
    const float* __restrict__ RM2, const float* __restrict__ RV2,
    float* __restrict__ vf0, float* __restrict__ vf1, float* __restrict__ vf2,
    const int* __restrict__ co0, const int* __restrict__ co1, const int* __restrict__ co2,
    int* __restrict__ win,
    int N0, int N1, int N2)
{
  __shared__ __align__(16) VfeLds vlds;
  int b = blockIdx.x;
  const int tid = threadIdx.x;

  if (b < 576) {               // ---- twt role (147,456 elems = 576*256 exact)
    int i = b * 256 + tid;
    int ciq = i & 31;
    int r = i >> 5;
    int co = r & 63; r >>= 6;
    int tap = r % 9; r /= 9;
    int qk = r & 3;
    int set = r >> 2;
    int ci = qk * 32 + ciq;
    fwT[i] = f2bf(fw[(((set * 64 + co) * 128 + ci) * 9) + tap]);
    return;
  }
  b -= 576;
  if (b < 3072) {              // ---- VFE role: scale = b>>10, 1024 blocks each
    int s = b >> 10, lb = b & 1023;
    const float* vox = (s == 0) ? vox0 : (s == 1) ? vox1 : vox2;
    const int* npts = (s == 0) ? np0 : (s == 1) ? np1 : np2;
    float* vf = (s == 0) ? vf0 : (s == 1) ? vf1 : vf2;
    int N = (s == 0) ? N0 : (s == 1) ? N1 : N2;
    vfe_body(vlds, lb, vox, npts,
             W1 + s * 576, G1 + s * 64, B1 + s * 64, RM1 + s * 64, RV1 + s * 64,
             W2 + s * 8192, G2 + s * 64, B2 + s * 64, RM2 + s * 64, RV2 + s * 64,
             vf, N);
    return;
  }
  b -= 3072;                   // ---- winner role over concatenated voxels
  int t = b * 256 + tid;
  if (t >= N0 + N1 + N2) return;
  const int* coords; int H, W; int* wn; int v;
  if (t < N0)            { coords = co0; H = 496; W = 432; wn = win; v = t; }
  else if (t < N0 + N1)  { coords = co1; H = 248; W = 216; wn = win + 4 * 496 * 432; v = t - N0; }
  else                   { coords = co2; H = 124; W = 108; wn = win + 4 * 496 * 432 + 4 * 248 * 216; v = t - N0 - N1; }
  int bb = coords[v * 4 + 0];
  int y = min(max(coords[v * 4 + 2], 0), H - 1);
  int x = min(max(coords[v * 4 + 3], 0), W - 1);
  atomicMax(&wn[(bb * H + y) * W + x], v);
}

// ---------------------------------------------------------------------------
// Fused scatter pass 2 + zero-fill over ALL scales (win buffers contiguous,
// global cell index selects scale). s0,s1 -> planar quarters; s2 -> dense.
// ---------------------------------------------------------------------------
__global__ void fillf_kernel(const int* __restrict__ win,
                             const float* __restrict__ vf0, const float* __restrict__ vf1,
                             const float* __restrict__ vf2,
                             u16* __restrict__ buf0, u16* __restrict__ buf1, u16* __restrict__ g2b,
                             int c0, int c1, int c2, size_t ps0, size_t ps1) {
  int i = blockIdx.x * blockDim.x + threadIdx.x;
  if (i >= (c0 + c1 + c2) * 8) return;
  int cellg = i >> 3, c8 = (i & 7) * 8;
  int wv = win[cellg];
  const float* vf; u16* d;
  if (cellg < c0) {
    vf = vf0;
    d = buf0 + (size_t)(c8 >> 5) * ps0 + (size_t)cellg * 32 + (c8 & 31);
  } else if (cellg < c0 + c1) {
    vf = vf1;
    d = buf1 + (size_t)(c8 >> 5) * ps1 + (size_t)(cellg - c0) * 32 + (c8 & 31);
  } else {
    vf = vf2;
    d = g2b + (size_t)(cellg - c0 - c1) * 64 + c8;
  }
  bf16x8 o = (bf16x8){0, 0, 0, 0, 0, 0, 0, 0};
  if (wv >= 0) {
    const float* p = vf + (size_t)wv * 64 + c8;
    float4 v0 = *(const float4*)p;
    float4 v1 = *(const float4*)(p + 4);
    o[0] = (short)f2bf(v0.x); o[1] = (short)f2bf(v0.y);
    o[2] = (short)f2bf(v0.z); o[3] = (short)f2bf(v0.w);
    o[4] = (short)f2bf(v1.x); o[5] = (short)f2bf(v1.y);
    o[6] = (short)f2bf(v1.z); o[7] = (short)f2bf(v1.w);
  }
  *(bf16x8*)d = o;
}

// ---------------------------------------------------------------------------
// Bilinear 2x upsample: src dense 64-ch NHWC; dst planar quarters 2,3
// (ch 64..127) of a 4-plane [cell][32ci] buffer with plane stride ps (u16).
// (unchanged, verified)
// ---------------------------------------------------------------------------
__global__ void upsample_kernel(const u16* __restrict__ src, u16* __restrict__ dst,
                                int Hc, int Wc, size_t ps, int total8) {
  int i = blockIdx.x * blockDim.x + threadIdx.x;
  if (i >= total8) return;
  int c8 = (i & 7) * 8;
  int px = i >> 3;
  int W2 = Wc * 2, H2 = Hc * 2;
  int x = px % W2; int t = px / W2; int y = t % H2; int n = t / H2;
  int ky = y >> 1, kx = x >> 1;
  int ya, yb, xa, xb; float wya, wxa;
  if ((y & 1) == 0) { ya = ky > 0 ? ky - 1 : 0; yb = ky; wya = 0.25f; }
  else              { ya = ky; yb = (ky + 1 < Hc) ? ky + 1 : Hc - 1; wya = 0.75f; }
  if ((x & 1) == 0) { xa = kx > 0 ? kx - 1 : 0; xb = kx; wxa = 0.25f; }
  else              { xa = kx; xb = (kx + 1 < Wc) ? kx + 1 : Wc - 1; wxa = 0.75f; }
  float wyb = 1.f - wya, wxb = 1.f - wxa;
  const u16* sp = src + c8;
  bf16x8 vaa = *(const bf16x8*)&sp[((size_t)(n * Hc + ya) * Wc + xa) * 64];
  bf16x8 vab = *(const bf16x8*)&sp[((size_t)(n * Hc + ya) * Wc + xb) * 64];
  bf16x8 vba = *(const bf16x8*)&sp[((size_t)(n * Hc + yb) * Wc + xa) * 64];
  bf16x8 vbb = *(const bf16x8*)&sp[((size_t)(n * Hc + yb) * Wc + xb) * 64];
  bf16x8 o;
#pragma unroll
  for (int j = 0; j < 8; ++j) {
    float v = wya * (wxa * bf2f((u16)vaa[j]) + wxb * bf2f((u16)vab[j])) +
              wyb * (wxa * bf2f((u16)vba[j]) + wxb * bf2f((u16)vbb[j]));
    o[j] = (short)f2bf(v);
  }
  *(bf16x8*)&dst[(size_t)(2 + (c8 >> 5)) * ps + (size_t)px * 32 + (c8 & 31)] = o;
}

// ---------------------------------------------------------------------------
// Conv3x3 + BN + ReLU, implicit GEMM with bf16 MFMA 16x16x32.
// (BYTE-IDENTICAL to round-9: M=64 wave, planar ci-quarters, 3 blocks/CU,
// 229us/31% occ/23.7 MfmaUtil verified. Untouched this round.)
// ---------------------------------------------------------------------------
template<int H, int W, bool NCHW_OUT>
__global__ __launch_bounds__(256, 3) void conv_kernel(
    const u16* __restrict__ in, const u16* __restrict__ wT,
    const float* __restrict__ fg, const float* __restrict__ fb,
    const float* __restrict__ fm, const float* __restrict__ fv,
    void* __restrict__ outv)
{
  constexpr int XT = 32, YT = 8;
  constexpr int XTILES = (W + XT - 1) / XT;
  constexpr int YTILES = H / YT;
  constexpr int HC = XT + 2;                   // 34 halo cols
  constexpr int NPX = (YT + 2) * HC;           // 340 halo positions
  const size_t PS = (size_t)4 * H * W * 32;    // plane stride (u16), batch=4
  __shared__ __align__(16) union {
    struct { char A[(NPX / 2) * 128]; char B[2][4096]; } s;  // 21,760 + 8,192 = 29,952
    float T[4 * 32 * 33];                      // 16,896 (NCHW epilogue, half-co)
  } lds;

  const int tid = threadIdx.x;
  const int lane = tid & 63;
  const int wv = tid >> 6;                     // wave -> rows [2wv, 2wv+1]
  const int m16 = lane & 15;
  const int q = lane >> 4;

  int bid = blockIdx.x;
  const int xt = bid % XTILES; bid /= XTILES;
  const int yt = bid % YTILES;
  const int n = bid / YTILES;
  const int x0 = xt * XT, y0 = yt * YT;

  // per-lane A-frag halo position (M-pos = mf*16+m16 -> row = mf>>1, px)
  int lin[4];
#pragma unroll
  for (int mf = 0; mf < 4; ++mf)
    lin[mf] = (2 * wv + (mf >> 1)) * HC + ((mf & 1) << 4) + m16;

  // per-lane B-frag byte base within a tap plane (co = nf*16+m16, k-slice q)
  const int bbase = ((m16 >> 1) << 7) + (((((m16 & 1) << 2) + q) ^ ((m16 >> 1) & 7)) << 4);

  f32x4 acc[4][4];
#pragma unroll
  for (int mf = 0; mf < 4; ++mf)
#pragma unroll
    for (int nf = 0; nf < 4; ++nf)
      acc[mf][nf] = (f32x4){0.f, 0.f, 0.f, 0.f};

  const int bco = tid >> 2, bs = tid & 3;      // B staging chunk coords
  const int bslot = ((((bco & 1) << 2) + bs) ^ ((bco >> 1) & 7));
  const int bldst = ((bco >> 1) << 7) + (bslot << 4);
  const int bgsrc = bco * 32 + bs * 8;         // u16 offset within tap plane

  for (int qk = 0; qk < 4; ++qk) {
    // protected by previous quarter's tap-8 barrier (or kernel entry)
    const u16* inq = in + (size_t)qk * PS;
    const u16* wq = wT + qk * (9 * 64 * 32);
    {
      // stage A: 340 px x 32 ci (64B/px), pair-packed swizzled 128B rows
#pragma unroll
      for (int it = 0; it < 6; ++it) {
        int c = tid + it * 256;
        if (c < NPX * 4) {
          int p = c >> 2, s = c & 3;
          int r = p / HC, xx = p - r * HC;
          int gy = y0 - 1 + r, gx = x0 - 1 + xx;
          uint4 v = make_uint4(0, 0, 0, 0);
          if (gy >= 0 && gy < H && gx >= 0 && gx < W)
            v = *(const uint4*)(inq + ((size_t)((n * H + gy) * W + gx)) * 32 + s * 8);
          int slot = (((p & 1) << 2) + s) ^ ((p >> 1) & 7);
          *(uint4*)(lds.s.A + ((p >> 1) << 7) + (slot << 4)) = v;
        }
      }
      // stage B tap 0 -> buffer 0 (one 16B chunk per thread)
      uint4 v = *(const uint4*)(wq + bgsrc);
      *(uint4*)(lds.s.B[0] + bldst) = v;
    }
    __syncthreads();                           // A + B[0] visible

#pragma unroll
    for (int tap = 0; tap < 9; ++tap) {
      // T14 issue-early: next tap's B -> reg before the MFMA cluster
      uint4 bv;
      if (tap < 8) bv = *(const uint4*)(wq + (tap + 1) * 2048 + bgsrc);
      const int tapofs = (tap / 3) * HC + (tap % 3);
      const char* Bb = lds.s.B[tap & 1];
      bf16x8 b[4], a[4];
#pragma unroll
      for (int nf = 0; nf < 4; ++nf)
        b[nf] = *(const bf16x8*)(Bb + (nf << 10) + bbase);
#pragma unroll
      for (int mf = 0; mf < 4; ++mf) {
        int hp = lin[mf] + tapofs;
        int slot = (((hp & 1) << 2) + q) ^ ((hp >> 1) & 7);
        a[mf] = *(const bf16x8*)(lds.s.A + ((hp >> 1) << 7) + (slot << 4));
      }
#pragma unroll
      for (int mf = 0; mf < 4; ++mf)
#pragma unroll
        for (int nf = 0; nf < 4; ++nf)
          acc[mf][nf] = __builtin_amdgcn_mfma_f32_16x16x32_bf16(a[mf], b[nf], acc[mf][nf], 0, 0, 0);
      // write-late: prefetched B into the other buffer (its readers ran in
      // tap-1, protected by tap-1's barrier)
      if (tap < 8) *(uint4*)(lds.s.B[(tap + 1) & 1] + bldst) = bv;
      __syncthreads();                         // B[next] visible; tap reads done
    }
  }

  // BN scale/shift in epilogue (keeps main-loop VGPR pressure down)
  float sc[4], sh[4];
#pragma unroll
  for (int nf = 0; nf < 4; ++nf) {
    int co = nf * 16 + m16;
    float s = fg[co] * rsqrtf(fv[co] + EPSV);
    sc[nf] = s;
    sh[nf] = fb[co] - fm[co] * s;
  }

  if (!NCHW_OUT) {
    // NHWC(64) bf16 direct store (internal fused1 buffer)
    u16* out = (u16*)outv;
#pragma unroll
    for (int mf = 0; mf < 4; ++mf) {
      int y = y0 + wv * 2 + (mf >> 1);
#pragma unroll
      for (int nf = 0; nf < 4; ++nf)
#pragma unroll
        for (int r = 0; r < 4; ++r) {
          int px = ((mf & 1) << 4) + q * 4 + r;
          int x = x0 + px;
          if (x < W) {
            int co = nf * 16 + m16;
            float v = fmaxf(acc[mf][nf][r] * sc[nf] + sh[nf], 0.f);
            out[((size_t)(n * H + y) * W + x) * 64 + co] = f2bf(v);
          }
        }
    }
  } else {
    // NCHW f32 d_out: per-row, per-co-half transpose via wave-private LDS
    __syncthreads();                           // all tap reads done; union reuse safe
    float* out = (float*)outv;
    float* T = &lds.T[wv * 32 * 33];
#pragma unroll
    for (int rr = 0; rr < 2; ++rr) {
      int y = y0 + wv * 2 + rr;
#pragma unroll
      for (int half = 0; half < 2; ++half) {
#pragma unroll
        for (int nfh = 0; nfh < 2; ++nfh) {
          int nf = half * 2 + nfh;
#pragma unroll
          for (int xc = 0; xc < 2; ++xc) {
            int mf = rr * 2 + xc;
#pragma unroll
            for (int r = 0; r < 4; ++r) {
              int px = (xc << 4) + q * 4 + r;
              int col = nfh * 16 + m16;
              T[col * 33 + px] = fmaxf(acc[mf][nf][r] * sc[nf] + sh[nf], 0.f);
            }
          }
        }
        WAVE_FENCE();
        const int px = lane & 31, co2 = lane >> 5;
        int x = x0 + px;
#pragma unroll 4
        for (int it = 0; it < 16; ++it) {
          int col = it * 2 + co2;
          int co = half * 32 + col;
          float v = T[col * 33 + px];
          if (x < W) out[((size_t)(n * 64 + co) * H + y) * W + x] = v;
        }
        WAVE_FENCE();
      }
    }
  }
}

// ---------------------------------------------------------------------------
extern "C" void kernel_launch(void* const* d_in, const int* in_sizes, int n_in,
                              void* d_out, int out_size, void* d_ws, size_t ws_size,
                              hipStream_t stream) {
  int I_vox[3], I_np[3], I_co[3];
  int I_w1, I_g1, I_b1, I_rm1, I_rv1, I_w2, I_g2, I_b2, I_rm2, I_rv2;
  int I_fw, I_fg, I_fb, I_fm, I_fv;
  if (in_sizes[1] == 40000) {
    I_vox[0] = 0; I_np[0] = 1; I_co[0] = 2;
    I_vox[1] = 3; I_np[1] = 4; I_co[1] = 5;
    I_vox[2] = 6; I_np[2] = 7; I_co[2] = 8;
    I_w1 = 9; I_g1 = 10; I_b1 = 11; I_rm1 = 12; I_rv1 = 13;
    I_w2 = 14; I_g2 = 15; I_b2 = 16; I_rm2 = 17; I_rv2 = 18;
    I_fw = 19; I_fg = 20; I_fb = 21; I_fm = 22; I_fv = 23;
  } else {
    I_vox[0] = 0; I_vox[1] = 1; I_vox[2] = 2;
    I_w1 = 3; I_g1 = 4; I_b1 = 5; I_rm1 = 6; I_rv1 = 7;
    I_w2 = 8; I_g2 = 9; I_b2 = 10; I_rm2 = 11; I_rv2 = 12;
    I_fw = 13; I_fg = 14; I_fb = 15; I_fm = 16; I_fv = 17;
    I_np[0] = 18; I_np[1] = 19; I_np[2] = 20;
    I_co[0] = 21; I_co[1] = 22; I_co[2] = 23;
  }

  const int HS[3] = {496, 248, 124};
  const int WS[3] = {432, 216, 108};
  int Nv[3];
  for (int s = 0; s < 3; ++s) Nv[s] = in_sizes[I_np[s]];

  char* wsp = (char*)d_ws;
  size_t off = 0;
  auto take = [&](size_t bytes) -> void* {
    void* p = wsp + off;
    off = (off + bytes + 255) & ~(size_t)255;
    return p;
  };
  float* vf[3];
  for (int s = 0; s < 3; ++s) vf[s] = (float*)take((size_t)Nv[s] * 64 * 4);
  int cells[3];
  for (int s = 0; s < 3; ++s) cells[s] = 4 * HS[s] * WS[s];
  int cellsTot = cells[0] + cells[1] + cells[2];
  int* win = (int*)take((size_t)cellsTot * 4);          // contiguous all scales
  u16* buf0 = (u16*)take((size_t)cells[0] * 128 * 2);   // 4 planes x (cells0 x 32ci) bf16
  u16* buf1 = (u16*)take((size_t)cells[1] * 128 * 2);   // 4 planes x (cells1 x 32ci)
  u16* g2b  = (u16*)take((size_t)cells[2] * 64 * 2);    // dense (4,124,108,64)
  u16* fus1 = (u16*)take((size_t)cells[1] * 64 * 2);    // dense (4,248,216,64)
  u16* fwT  = (u16*)take((size_t)2 * 4 * 9 * 64 * 32 * 2);

  const float* W1 = (const float*)d_in[I_w1];
  const float* G1 = (const float*)d_in[I_g1];
  const float* B1 = (const float*)d_in[I_b1];
  const float* RM1 = (const float*)d_in[I_rm1];
  const float* RV1 = (const float*)d_in[I_rv1];
  const float* W2 = (const float*)d_in[I_w2];
  const float* G2 = (const float*)d_in[I_g2];
  const float* B2 = (const float*)d_in[I_b2];
  const float* RM2 = (const float*)d_in[I_rm2];
  const float* RV2 = (const float*)d_in[I_rv2];
  const float* FW = (const float*)d_in[I_fw];
  const float* FG = (const float*)d_in[I_fg];
  const float* FB = (const float*)d_in[I_fb];
  const float* FM = (const float*)d_in[I_fm];
  const float* FV = (const float*)d_in[I_fv];

  hipMemsetAsync(win, 0xFF, (size_t)cellsTot * 4, stream);

  {   // mega-kernel: twt + 3xVFE (concurrent) + 3xwinner
    int winB = (Nv[0] + Nv[1] + Nv[2] + 255) / 256;
    fused1_kernel<<<576 + 3072 + winB, 256, 0, stream>>>(
        FW, fwT,
        (const float*)d_in[I_vox[0]], (const float*)d_in[I_vox[1]], (const float*)d_in[I_vox[2]],
        (const int*)d_in[I_np[0]], (const int*)d_in[I_np[1]], (const int*)d_in[I_np[2]],
        W1, G1, B1, RM1, RV1, W2, G2, B2, RM2, RV2,
        vf[0], vf[1], vf[2],
        (const int*)d_in[I_co[0]], (const int*)d_in[I_co[1]], (const int*)d_in[I_co[2]],
        win, Nv[0], Nv[1], Nv[2]);
  }

  const size_t ps0 = (size_t)cells[0] * 32;
  const size_t ps1 = (size_t)cells[1] * 32;
  fillf_kernel<<<(cellsTot * 8 + 255) / 256, 256, 0, stream>>>(
      win, vf[0], vf[1], vf[2], buf0, buf1, g2b, cells[0], cells[1], cells[2], ps0, ps1);

  {   // upsample g2 (124,108) -> buf1 planes 2,3 (248,216)
    int total8 = cells[1] * 8;
    upsample_kernel<<<(total8 + 255) / 256, 256, 0, stream>>>(g2b, buf1, 124, 108, ps1, total8);
  }
  conv_kernel<248, 216, false><<<4 * (248 / 8) * 7, 256, 0, stream>>>(
      buf1, fwT + 4 * 9 * 64 * 32, FG + 64, FB + 64, FM + 64, FV + 64, fus1);
  {   // upsample fused1 (248,216) -> buf0 planes 2,3 (496,432)
    int total8 = cells[0] * 8;
    upsample_kernel<<<(total8 + 255) / 256, 256, 0, stream>>>(fus1, buf0, 248, 216, ps0, total8);
  }
  conv_kernel<496, 432, true><<<4 * (496 / 8) * 14, 256, 0, stream>>>(
      buf0, fwT, FG, FB, FM, FV, (float*)d_out);
}